// Round 6
// baseline (292.251 us; speedup 1.0000x reference)
//
#include <hip/hip_runtime.h>

// Shift op: out[n, c*9 + s, h, w] = x_pad[n, c, h + s/3, w + s%3], pad=1.
// x: (32, 64, 56, 56) fp32 -> out: (32, 576, 56, 56).
//
// R5->R6: MEASUREMENT PROBE. Identical kernel to R5 (LDS-staged, linear
// stores) but launched TWICE per call (idempotent). The timed increment over
// R5's 246.2 us is the kernel's true standalone duration, which the top-5
// profile (dominated by 143-us harness poison fills) cannot show us.

#define N_ 32
#define C_ 64
#define H_ 56
#define W_ 56
#define W4 14                      // float4s per row
#define PLANE (H_ * W_)            // 3136 floats per (n,c) plane
#define PLANE4 (H_ * W4)           // 784 float4s per plane
#define LROW 68                    // LDS row stride (floats)
#define LROWS 58                   // padded rows
#define LSIZE (LROWS * LROW)       // 3944 floats = 15.8 KB

typedef float f4 __attribute__((ext_vector_type(4)));

__global__ __launch_bounds__(256) void shift_kernel(const float* __restrict__ x,
                                                    f4* __restrict__ out) {
    __shared__ float lds[LSIZE];
    const int tid = threadIdx.x;
    const int nc  = blockIdx.x;           // 0 .. N_*C_-1

    // 1) zero the whole tile (border must be 0)
    for (int i = tid; i < LSIZE; i += 256) lds[i] = 0.f;
    __syncthreads();

    // 2) stage the plane: interior at lds[(h+1)*LROW + 4 + w]
    const f4* src = (const f4*)(x + (long)nc * PLANE);
    for (int i = tid; i < PLANE4; i += 256) {
        int h  = i / W4;
        int w4 = i % W4;
        f4 v = src[i];
        *(f4*)&lds[(h + 1) * LROW + 4 + 4 * w4] = v;   // 16B-aligned (LROW%4==0)
    }
    __syncthreads();

    // 3) emit 9 shifted planes, fully linear stores
    f4* ob = out + (long)nc * 9 * PLANE4;
#pragma unroll
    for (int s = 0; s < 9; ++s) {
        const int dyi = s / 3;      // 0..2  (lds row = h + dyi)
        const int dxi = s % 3;      // 0..2  (lds col = 3 + w + dxi)
        f4* op = ob + (long)s * PLANE4;
        for (int i = tid; i < PLANE4; i += 256) {
            int h  = i / W4;
            int w0 = 4 * (i % W4);
            const float* p = &lds[(h + dyi) * LROW + 3 + dxi + w0];
            f4 v = { p[0], p[1], p[2], p[3] };
            __builtin_nontemporal_store(v, op + i);
        }
    }
}

extern "C" void kernel_launch(void* const* d_in, const int* in_sizes, int n_in,
                              void* d_out, int out_size, void* d_ws, size_t ws_size,
                              hipStream_t stream) {
    const float* x = (const float*)d_in[0];
    f4* out = (f4*)d_out;
    shift_kernel<<<N_ * C_, 256, 0, stream>>>(x, out);
    shift_kernel<<<N_ * C_, 256, 0, stream>>>(x, out);   // probe: 2nd identical launch
}

// Round 7
// 242.798 us; speedup vs baseline: 1.2037x; 1.2037x over previous
//
#include <hip/hip_runtime.h>

// Shift op: out[n, c*9 + s, h, w] = x_pad[n, c, h + s/3, w + s%3], pad=1.
// x: (32, 64, 56, 56) fp32 -> out: (32, 576, 56, 56).
//
// FINAL (R6->R7): revert R6's 2x-launch measurement probe; single launch of
// the R3 kernel. Probe established kernel standalone duration ~46 us vs
// 39.8 us ideal (257 MB mixed traffic at the harness fill's measured
// 6.45 TB/s) => ~87% of achievable HBM ceiling; write-BW-bound floor.
// Three structurally different variants (global-reread+nt, +plain,
// LDS-staged linear) all measured identical => memory floor, not a
// software limiter.
//
// Structure: one thread per INPUT (n,c,h,w4) float4. Each thread loads a
// 3x6 float window (aligned float4 + 2 edge scalars per row, L1-served)
// and emits all 9 shifted output float4s via register selection +
// coalesced nontemporal dwordx4 stores.

#define N_ 32
#define C_ 64
#define H_ 56
#define W_ 56
#define W4 14                      // float4s per row
#define PLANE (H_ * W_)            // 3136 floats per (n,c) plane
#define POS_PER_PLANE (H_ * W4)    // 784
#define TOTAL (N_ * C_ * POS_PER_PLANE)  // 1,605,632 threads

typedef float f4 __attribute__((ext_vector_type(4)));

__global__ __launch_bounds__(256) void shift_kernel(const float* __restrict__ x,
                                                    float* __restrict__ out) {
    int t = blockIdx.x * blockDim.x + threadIdx.x;
    if (t >= TOTAL) return;

    int w4 = t % W4;
    int r  = t / W4;
    int h  = r % H_;
    int nc = r / H_;

    int w0 = w4 * 4;
    const float* plane = x + (long)nc * PLANE;

    // rowbuf[d][j] = x[nc, h+d-1, w0-1+j] (zero-padded), j in [0,6)
    float rowbuf[3][6];
#pragma unroll
    for (int d = 0; d < 3; ++d) {
        int ih = h + d - 1;
        if (ih < 0 || ih >= H_) {
#pragma unroll
            for (int j = 0; j < 6; ++j) rowbuf[d][j] = 0.f;
        } else {
            const float* rp = plane + ih * W_;
            f4 v = *(const f4*)(rp + w0);   // aligned 16B load
            rowbuf[d][1] = v.x;
            rowbuf[d][2] = v.y;
            rowbuf[d][3] = v.z;
            rowbuf[d][4] = v.w;
            rowbuf[d][0] = (w4 > 0)      ? rp[w0 - 1] : 0.f;
            rowbuf[d][5] = (w4 < W4 - 1) ? rp[w0 + 4] : 0.f;
        }
    }

    // out flat index for (nc, s, h, w0): ((nc*9 + s)*H_ + h)*W_ + w0
    float* ob = out + ((long)(nc * 9) * H_ + h) * W_ + w0;
#pragma unroll
    for (int dy = 0; dy < 3; ++dy) {
#pragma unroll
        for (int dx = 0; dx < 3; ++dx) {
            f4 v = { rowbuf[dy][dx],     rowbuf[dy][dx + 1],
                     rowbuf[dy][dx + 2], rowbuf[dy][dx + 3] };
            __builtin_nontemporal_store(v, (f4*)(ob + (long)(dy * 3 + dx) * PLANE));
        }
    }
}

extern "C" void kernel_launch(void* const* d_in, const int* in_sizes, int n_in,
                              void* d_out, int out_size, void* d_ws, size_t ws_size,
                              hipStream_t stream) {
    const float* x = (const float*)d_in[0];
    float* out = (float*)d_out;

    int block = 256;
    int grid = (TOTAL + block - 1) / block;   // 6272 blocks exactly
    shift_kernel<<<grid, block, 0, stream>>>(x, out);
}